// Round 1
// baseline (7151.768 us; speedup 1.0000x reference)
//
#include <hip/hip_runtime.h>
#include <hip/hip_bf16.h>
#include <math.h>

typedef __bf16 bf16x8 __attribute__((ext_vector_type(8)));
typedef __bf16 bf16x4 __attribute__((ext_vector_type(4)));
typedef float f32x4 __attribute__((ext_vector_type(4)));

#define S_LEN 128
#define BATCH 32
#define E2C 1024
#define DH 512
#define AH 32
#define EMBD 256
#define VOC 32000
#define TMAX 48
#define NCHUNK 125   /* VOC / 256 */
#define NBLK 128     /* persistent grid size */

#define MFMA16(a, b, c) __builtin_amdgcn_mfma_f32_16x16x32_bf16((a), (b), (c), 0, 0, 0)

// ---- workspace layout (bytes) ----
#define OFF_HF0   0
#define OFF_HH0   65536
#define OFF_HL0   98304
#define OFF_HF1   131072
#define OFF_HH1   196608
#define OFF_HL1   229376
#define OFF_XH    262144
#define OFF_XL    344064
#define OFF_ENCW1 425984
#define OFF_PVAL  950272
#define OFF_PIDX  966656
#define OFF_BAR   983040            /* 128 B: cnt @ +0, gen @ +64 */
#define OFF_WOH   983168
#define OFF_WOL   33751168
#define OFF_WIHH  66519168
#define OFF_WIHL  70451328
#define OFF_WHHH  74383488
#define OFF_WHHL  75956352
#define WS_REQ    77529216ULL

// Split 8 consecutive f32 into bf16 hi + bf16 lo (x = hi + lo + O(2^-18 x)).
__device__ __forceinline__ void split8(const float* __restrict__ p,
                                       bf16x8& hi, bf16x8& lo) {
  const f32x4 v0 = *(const f32x4*)p;
  const f32x4 v1 = *(const f32x4*)(p + 4);
  float t[8] = {v0[0], v0[1], v0[2], v0[3], v1[0], v1[1], v1[2], v1[3]};
  #pragma unroll
  for (int i = 0; i < 8; i++) {
    const __bf16 h = (__bf16)t[i];
    hi[i] = h;
    lo[i] = (__bf16)(t[i] - (float)h);
  }
}

// Device-scope grid barrier: monotonic arrival counter + generation flag.
// All NBLK blocks are co-resident (128 blocks <= 256 CUs, 32KiB LDS, 256 thr),
// so the spin cannot deadlock; spin is additionally bounded as a failsafe.
__device__ __forceinline__ void gridbar(unsigned* cnt, unsigned* gen, unsigned target) {
  __syncthreads();
  if (threadIdx.x == 0) {
    __threadfence();   // release: make this block's stores device-visible
    const unsigned prev =
        __hip_atomic_fetch_add(cnt, 1u, __ATOMIC_ACQ_REL, __HIP_MEMORY_SCOPE_AGENT);
    if (prev == target * NBLK - 1u) {
      __hip_atomic_store(gen, target, __ATOMIC_RELEASE, __HIP_MEMORY_SCOPE_AGENT);
    } else {
      int guard = 0;
      while (__hip_atomic_load(gen, __ATOMIC_ACQUIRE, __HIP_MEMORY_SCOPE_AGENT) < target &&
             ++guard < (1 << 20)) {
        __builtin_amdgcn_s_sleep(4);
      }
    }
    __threadfence();   // acquire: invalidate stale cache lines before reads
  }
  __syncthreads();
}

// ---------------------------------------------------------------------------
// K_init: zero h-state block (hf0|hh0|hl0 = 131072 B) + barrier words.
// ---------------------------------------------------------------------------
__global__ __launch_bounds__(256) void k_init(unsigned int* __restrict__ p,
                                              unsigned int* __restrict__ bar) {
  p[blockIdx.x * 256 + threadIdx.x] = 0u;
  if (blockIdx.x == 0 && threadIdx.x < 32) bar[threadIdx.x] = 0u;
}

// ---------------------------------------------------------------------------
// K0: encW1[s,b,j] = sum_k enc[s,b,k] * W1[j, DH+k]   (hoisted out of t-loop)
// ---------------------------------------------------------------------------
__global__ __launch_bounds__(256) void k_encw1(const float* __restrict__ enc,
                                               const float* __restrict__ W1,
                                               float* __restrict__ encW1) {
  __shared__ float el[E2C];
  __shared__ float red[256];
  const int tid = threadIdx.x;
  const int blk = blockIdx.x;                       // s*BATCH + b
  for (int i = 0; i < 4; i++)
    el[tid + i * 256] = enc[(size_t)blk * E2C + tid + i * 256];
  __syncthreads();
  const int j = tid >> 3, c = tid & 7;
  const float* wrow = W1 + (size_t)j * (DH + E2C) + DH;
  float p = 0.f;
  for (int k = c * 128; k < c * 128 + 128; k++) p += el[k] * wrow[k];
  red[tid] = p;
  __syncthreads();
  if (c < 4) red[tid] += red[tid + 4];
  __syncthreads();
  if (c < 2) red[tid] += red[tid + 2];
  __syncthreads();
  if (c == 0) encW1[(size_t)blk * AH + j] = red[tid] + red[tid + 1];
}

// ---------------------------------------------------------------------------
// K_split4: one-time f32 -> (bf16 hi, bf16 lo) split, 4 elements/thread.
// Identical math to split8 -> bit-identical downstream results.
// ---------------------------------------------------------------------------
__global__ __launch_bounds__(256) void k_split4(const float* __restrict__ src,
                                                __bf16* __restrict__ dh,
                                                __bf16* __restrict__ dl, int n4) {
  const int i = blockIdx.x * 256 + threadIdx.x;
  if (i >= n4) return;
  const f32x4 v = ((const f32x4*)src)[i];
  bf16x4 h4, l4;
  #pragma unroll
  for (int j = 0; j < 4; j++) {
    const float x = v[j];
    const __bf16 h = (__bf16)x;
    h4[j] = h;
    l4[j] = (__bf16)(x - (float)h);
  }
  *(bf16x4*)(dh + (size_t)i * 4) = h4;
  *(bf16x4*)(dl + (size_t)i * 4) = l4;
}

// ---------------------------------------------------------------------------
// K_fused: all 48 decode steps in one persistent kernel.
//   phase ATTN  : 128 blocks (4 per batch: A/B/C duplicated, D split 4-way)
//   phase GRU   : blocks 0..31  (16 d-rows each, K-split-4 over waves)
//   phase LOGITS: blocks 0..124 (256 vocab rows each)
// 3 grid barriers per step. PRE: weights pre-split to bf16 hi/lo in ws.
// ---------------------------------------------------------------------------
template<bool PRE>
__global__ __launch_bounds__(256) void k_fused(
    const float* __restrict__ enc, const int* __restrict__ sos,
    const float* __restrict__ emb,
    const float* __restrict__ W1, const float* __restrict__ b1,
    const float* __restrict__ W2, const float* __restrict__ b2,
    const float* __restrict__ Wih, const float* __restrict__ bih,
    const float* __restrict__ Whh, const float* __restrict__ bhh,
    const float* __restrict__ Wo, const float* __restrict__ bo,
    float* __restrict__ out, char* __restrict__ ws) {
  __shared__ union {
    struct { float hs[DH]; float hw[AH]; float sc[S_LEN]; float red[256]; int ri[128]; int s_id; } a;
    float g[4][8][256];
    struct { float lv[128]; int li[128]; } l;
  } sm;

  float*  hf0 = (float*)(ws + OFF_HF0);
  __bf16* hh0 = (__bf16*)(ws + OFF_HH0);
  __bf16* hl0 = (__bf16*)(ws + OFF_HL0);
  float*  hf1 = (float*)(ws + OFF_HF1);
  __bf16* hh1 = (__bf16*)(ws + OFF_HH1);
  __bf16* hl1 = (__bf16*)(ws + OFF_HL1);
  __bf16* xh = (__bf16*)(ws + OFF_XH);
  __bf16* xl = (__bf16*)(ws + OFF_XL);
  const float* encW1 = (const float*)(ws + OFF_ENCW1);
  float* pval = (float*)(ws + OFF_PVAL);
  int*   pidx = (int*)(ws + OFF_PIDX);
  unsigned* bcnt = (unsigned*)(ws + OFF_BAR);
  unsigned* bgen = (unsigned*)(ws + OFF_BAR + 64);
  const __bf16* Woh  = (const __bf16*)(ws + OFF_WOH);
  const __bf16* Wol  = (const __bf16*)(ws + OFF_WOL);
  const __bf16* Wihh = (const __bf16*)(ws + OFF_WIHH);
  const __bf16* Wihl = (const __bf16*)(ws + OFF_WIHL);
  const __bf16* Whhh = (const __bf16*)(ws + OFF_WHHH);
  const __bf16* Whhl = (const __bf16*)(ws + OFF_WHHL);

  const int tid = threadIdx.x;
  const int blk = blockIdx.x;
  unsigned bars = 0;

  for (int t = 0; t < TMAX; t++) {
    const int p = t & 1;
    float*  hf_p = p ? hf1 : hf0;   // state in  (parity p)
    float*  hf_n = p ? hf0 : hf1;   // state out (parity p^1)
    __bf16* hh_p = p ? hh1 : hh0;
    __bf16* hh_n = p ? hh0 : hh1;
    __bf16* hl_p = p ? hl1 : hl0;
    __bf16* hl_n = p ? hl0 : hl1;

    // ==================== ATTN (all 128 blocks, 4 per batch) =============
    {
      const int b = blk >> 2;
      const int part = blk & 3;
      // Phase A (part 0 only): argmax feedback -> embedding rows of x
      if (part == 0) {
        if (t == 0) {
          if (tid == 0) sm.a.s_id = sos[0];
        } else {
          if (tid < 128) {
            if (tid < NCHUNK) { sm.a.red[tid] = pval[b * 128 + tid]; sm.a.ri[tid] = pidx[b * 128 + tid]; }
            else              { sm.a.red[tid] = -INFINITY;           sm.a.ri[tid] = 0x7fffffff; }
          }
          __syncthreads();
          for (int off = 64; off >= 1; off >>= 1) {
            if (tid < off) {
              const float ov = sm.a.red[tid + off]; const int oi = sm.a.ri[tid + off];
              if (ov > sm.a.red[tid] || (ov == sm.a.red[tid] && oi < sm.a.ri[tid])) {
                sm.a.red[tid] = ov; sm.a.ri[tid] = oi;
              }
            }
            __syncthreads();
          }
          if (tid == 0) sm.a.s_id = sm.a.ri[0];
        }
        __syncthreads();
        int id = sm.a.s_id;
        if (id < 0 || id >= VOC) id = 0;
        const float ev = emb[(size_t)id * EMBD + tid];
        const __bf16 eh = (__bf16)ev;
        xh[b * 1280 + 1024 + tid] = eh;
        xl[b * 1280 + 1024 + tid] = (__bf16)(ev - (float)eh);
      }
      // Phase B: hW1[j] = h[b,:] . W1[j,0:DH] + b1[j]   (duplicated per part)
      sm.a.hs[tid]       = hf_p[b * DH + tid];
      sm.a.hs[tid + 256] = hf_p[b * DH + tid + 256];
      __syncthreads();
      {
        const int j = tid >> 3, c = tid & 7;
        const float* wrow = W1 + (size_t)j * (DH + E2C);
        float pp = 0.f;
        for (int k = c * 64; k < c * 64 + 64; k++) pp += sm.a.hs[k] * wrow[k];
        sm.a.red[tid] = pp;
      }
      __syncthreads();
      if ((tid & 7) < 4) sm.a.red[tid] += sm.a.red[tid + 4];
      __syncthreads();
      if ((tid & 7) < 2) sm.a.red[tid] += sm.a.red[tid + 2];
      __syncthreads();
      if ((tid & 7) == 0) sm.a.hw[tid >> 3] = sm.a.red[tid] + sm.a.red[tid + 1] + b1[tid >> 3];
      __syncthreads();
      // Phase C: scores + softmax over S (duplicated per part)
      float ex = 0.f;
      if (tid < S_LEN) {
        const float* ew = encW1 + ((size_t)tid * BATCH + b) * AH;
        float sum = b2[0];
        #pragma unroll
        for (int j = 0; j < AH; j++) {
          const float v = ew[j] + sm.a.hw[j];
          sum += fmaxf(v, 0.f) * W2[j];
        }
        sm.a.sc[tid] = sum;
      }
      __syncthreads();
      if (tid < 128) sm.a.red[tid] = sm.a.sc[tid];
      __syncthreads();
      for (int off = 64; off >= 1; off >>= 1) {
        if (tid < off) sm.a.red[tid] = fmaxf(sm.a.red[tid], sm.a.red[tid + off]);
        __syncthreads();
      }
      const float mx = sm.a.red[0];
      __syncthreads();
      if (tid < 128) { ex = expf(sm.a.sc[tid] - mx); sm.a.red[tid] = ex; }
      __syncthreads();
      for (int off = 64; off >= 1; off >>= 1) {
        if (tid < off) sm.a.red[tid] += sm.a.red[tid + off];
        __syncthreads();
      }
      const float ssum = sm.a.red[0];
      if (tid < 128) sm.a.sc[tid] = ex / ssum;
      __syncthreads();
      // Phase D: context quarter [part*256, part*256+256), 1 element/thread
      const int e0 = part * 256 + tid;
      float aa = 0.f;
      for (int s = 0; s < S_LEN; s++)
        aa += sm.a.sc[s] * enc[((size_t)s * BATCH + b) * E2C + e0];
      const __bf16 ch = (__bf16)aa;
      xh[b * 1280 + e0] = ch;
      xl[b * 1280 + e0] = (__bf16)(aa - (float)ch);
    }
    gridbar(bcnt, bgen, ++bars);

    // ==================== GRU (blocks 0..31) =============================
    if (blk < 32) {
      const int wv = tid >> 6, lane = tid & 63, q = lane >> 4, ln = lane & 15;
      const int d = blk * 16 + ln;
      f32x4 acc[4][2];
      const f32x4 z4 = {0.f, 0.f, 0.f, 0.f};
      #pragma unroll
      for (int tt = 0; tt < 4; tt++) { acc[tt][0] = z4; acc[tt][1] = z4; }
      #pragma unroll
      for (int i = 0; i < 14; i++) {
        const int ka = wv * 32 + i * 128 + q * 8;
        bf16x8 ah0, al0, ah1, al1;
        if (i < 10) {
          ah0 = *(const bf16x8*)(xh + ln * 1280 + ka);
          ah1 = *(const bf16x8*)(xh + (16 + ln) * 1280 + ka);
          al0 = *(const bf16x8*)(xl + ln * 1280 + ka);
          al1 = *(const bf16x8*)(xl + (16 + ln) * 1280 + ka);
        } else {
          const int kb = ka - 1280;
          ah0 = *(const bf16x8*)(hh_p + ln * 512 + kb);
          ah1 = *(const bf16x8*)(hh_p + (16 + ln) * 512 + kb);
          al0 = *(const bf16x8*)(hl_p + ln * 512 + kb);
          al1 = *(const bf16x8*)(hl_p + (16 + ln) * 512 + kb);
        }
        #pragma unroll
        for (int g = 0; g < 3; g++) {
          bf16x8 bh, bl;
          if (PRE) {
            if (i < 10) {
              bh = *(const bf16x8*)(Wihh + (size_t)(g * 512 + d) * 1280 + ka);
              bl = *(const bf16x8*)(Wihl + (size_t)(g * 512 + d) * 1280 + ka);
            } else {
              bh = *(const bf16x8*)(Whhh + (size_t)(g * 512 + d) * 512 + (ka - 1280));
              bl = *(const bf16x8*)(Whhl + (size_t)(g * 512 + d) * 512 + (ka - 1280));
            }
          } else {
            if (i < 10) split8(Wih + (size_t)(g * 512 + d) * 1280 + ka, bh, bl);
            else        split8(Whh + (size_t)(g * 512 + d) * 512 + (ka - 1280), bh, bl);
          }
          const int tt = (g < 2) ? g : ((i < 10) ? 2 : 3);
          acc[tt][0] = MFMA16(ah0, bh, acc[tt][0]);
          acc[tt][0] = MFMA16(al0, bh, acc[tt][0]);
          acc[tt][0] = MFMA16(ah0, bl, acc[tt][0]);
          acc[tt][1] = MFMA16(ah1, bh, acc[tt][1]);
          acc[tt][1] = MFMA16(al1, bh, acc[tt][1]);
          acc[tt][1] = MFMA16(ah1, bl, acc[tt][1]);
        }
      }
      #pragma unroll
      for (int tt = 0; tt < 4; tt++)
        #pragma unroll
        for (int mt = 0; mt < 2; mt++)
          #pragma unroll
          for (int r = 0; r < 4; r++)
            sm.g[wv][tt * 2 + mt][(q * 4 + r) * 16 + ln] = acc[tt][mt][r];
      __syncthreads();
      for (int idx = tid; idx < 8 * 256; idx += 256) {
        const int tt = idx >> 8, e2 = idx & 255;
        sm.g[0][tt][e2] += sm.g[1][tt][e2] + sm.g[2][tt][e2] + sm.g[3][tt][e2];
      }
      __syncthreads();
      for (int u = tid; u < 512; u += 256) {
        const int bb = u >> 4, dd = u & 15;
        const int mt = bb >> 4;
        const int e2 = (bb & 15) * 16 + dd;
        const int dg = blk * 16 + dd;
        const float rp  = sm.g[0][0 * 2 + mt][e2] + bih[dg]          + bhh[dg];
        const float zp  = sm.g[0][1 * 2 + mt][e2] + bih[DH + dg]     + bhh[DH + dg];
        const float gin = sm.g[0][2 * 2 + mt][e2] + bih[2 * DH + dg];
        const float ghn = sm.g[0][3 * 2 + mt][e2] + bhh[2 * DH + dg];
        const float rg = 1.f / (1.f + expf(-rp));
        const float zg = 1.f / (1.f + expf(-zp));
        const float ng = tanhf(gin + rg * ghn);
        const float hp = hf_p[bb * DH + dg];
        const float hn = (1.f - zg) * ng + zg * hp;
        hf_n[bb * DH + dg] = hn;
        const __bf16 hhv = (__bf16)hn;
        hh_n[bb * DH + dg] = hhv;
        hl_n[bb * DH + dg] = (__bf16)(hn - (float)hhv);
      }
    }
    gridbar(bcnt, bgen, ++bars);

    // ==================== LOGITS (blocks 0..124) =========================
    if (blk < NCHUNK) {
      const int w = tid >> 6, lane = tid & 63, quad = lane >> 4, ln = lane & 15;
      const int v0 = blk * 256;
      float* outp = out + (size_t)t * BATCH * VOC;
      f32x4 acc[2][4];
      const f32x4 z4 = {0.f, 0.f, 0.f, 0.f};
      #pragma unroll
      for (int m = 0; m < 2; m++)
        #pragma unroll
        for (int n = 0; n < 4; n++) acc[m][n] = z4;
      for (int kk = 0; kk < 512; kk += 32) {
        const int ka = kk + quad * 8;
        const bf16x8 fh0 = *(const bf16x8*)(hh_n + ln * 512 + ka);
        const bf16x8 fh1 = *(const bf16x8*)(hh_n + (16 + ln) * 512 + ka);
        const bf16x8 fl0 = *(const bf16x8*)(hl_n + ln * 512 + ka);
        const bf16x8 fl1 = *(const bf16x8*)(hl_n + (16 + ln) * 512 + ka);
        #pragma unroll
        for (int nt = 0; nt < 4; nt++) {
          const int vr = v0 + (w * 4 + nt) * 16 + ln;
          bf16x8 bh, bl;
          if (PRE) {
            bh = *(const bf16x8*)(Woh + (size_t)vr * 512 + ka);
            bl = *(const bf16x8*)(Wol + (size_t)vr * 512 + ka);
          } else {
            split8(Wo + (size_t)vr * 512 + ka, bh, bl);
          }
          acc[0][nt] = MFMA16(fh0, bh, acc[0][nt]);
          acc[0][nt] = MFMA16(fl0, bh, acc[0][nt]);
          acc[0][nt] = MFMA16(fh0, bl, acc[0][nt]);
          acc[1][nt] = MFMA16(fh1, bh, acc[1][nt]);
          acc[1][nt] = MFMA16(fl1, bh, acc[1][nt]);
          acc[1][nt] = MFMA16(fh1, bl, acc[1][nt]);
        }
      }
      float bv[2][4]; int bi[2][4];
      #pragma unroll
      for (int m = 0; m < 2; m++)
        #pragma unroll
        for (int r = 0; r < 4; r++) { bv[m][r] = -INFINITY; bi[m][r] = 0x7fffffff; }
      #pragma unroll
      for (int nt = 0; nt < 4; nt++) {           // ascending v -> strict > keeps lowest idx
        const int v = v0 + (w * 4 + nt) * 16 + ln;
        const float bias = bo[v];
        #pragma unroll
        for (int mt = 0; mt < 2; mt++) {
          #pragma unroll
          for (int r = 0; r < 4; r++) {
            const float val = acc[mt][nt][r] + bias;
            const int bb = mt * 16 + quad * 4 + r;
            outp[(size_t)bb * VOC + v] = val;
            if (val > bv[mt][r]) { bv[mt][r] = val; bi[mt][r] = v; }
          }
        }
      }
      #pragma unroll
      for (int m = 1; m < 16; m <<= 1) {
        #pragma unroll
        for (int mt = 0; mt < 2; mt++) {
          #pragma unroll
          for (int r = 0; r < 4; r++) {
            const float ov = __shfl_xor(bv[mt][r], m, 64);
            const int oi = __shfl_xor(bi[mt][r], m, 64);
            if (ov > bv[mt][r] || (ov == bv[mt][r] && oi < bi[mt][r])) {
              bv[mt][r] = ov; bi[mt][r] = oi;
            }
          }
        }
      }
      if (ln == 0) {
        #pragma unroll
        for (int mt = 0; mt < 2; mt++)
          for (int r = 0; r < 4; r++) {
            const int bb = mt * 16 + quad * 4 + r;
            sm.l.lv[w * 32 + bb] = bv[mt][r];
            sm.l.li[w * 32 + bb] = bi[mt][r];
          }
      }
      __syncthreads();
      if (tid < 32) {
        float bbv = sm.l.lv[tid]; int bbi = sm.l.li[tid];
        for (int w2 = 1; w2 < 4; w2++) {         // ascending wave -> ascending v
          const float ov = sm.l.lv[w2 * 32 + tid]; const int oi = sm.l.li[w2 * 32 + tid];
          if (ov > bbv || (ov == bbv && oi < bbi)) { bbv = ov; bbi = oi; }
        }
        pval[tid * 128 + blk] = bbv;
        pidx[tid * 128 + blk] = bbi;
      }
    }
    gridbar(bcnt, bgen, ++bars);
  }
}

// ---------------------------------------------------------------------------
extern "C" void kernel_launch(void* const* d_in, const int* in_sizes, int n_in,
                              void* d_out, int out_size, void* d_ws, size_t ws_size,
                              hipStream_t stream) {
  const float* enc = (const float*)d_in[0];
  const int* sos = (const int*)d_in[2];
  const float* emb = (const float*)d_in[3];
  const float* W1 = (const float*)d_in[4];
  const float* b1 = (const float*)d_in[5];
  const float* W2 = (const float*)d_in[6];
  const float* b2 = (const float*)d_in[7];
  const float* Wih = (const float*)d_in[8];
  const float* bih = (const float*)d_in[9];
  const float* Whh = (const float*)d_in[10];
  const float* bhh = (const float*)d_in[11];
  const float* Wo = (const float*)d_in[12];
  const float* bo = (const float*)d_in[13];

  char* ws = (char*)d_ws;
  float* out = (float*)d_out;

  k_init<<<128, 256, 0, stream>>>((unsigned*)ws, (unsigned*)(ws + OFF_BAR));
  k_encw1<<<S_LEN * BATCH, 256, 0, stream>>>(enc, W1, (float*)(ws + OFF_ENCW1));

  if (ws_size >= WS_REQ) {
    // one-time f32 -> bf16 hi/lo pre-split of the big weights
    k_split4<<<16000, 256, 0, stream>>>(Wo,  (__bf16*)(ws + OFF_WOH),  (__bf16*)(ws + OFF_WOL),  4096000);
    k_split4<<<1920,  256, 0, stream>>>(Wih, (__bf16*)(ws + OFF_WIHH), (__bf16*)(ws + OFF_WIHL), 491520);
    k_split4<<<768,   256, 0, stream>>>(Whh, (__bf16*)(ws + OFF_WHHH), (__bf16*)(ws + OFF_WHHL), 196608);
    k_fused<true><<<NBLK, 256, 0, stream>>>(enc, sos, emb, W1, b1, W2, b2,
                                            Wih, bih, Whh, bhh, Wo, bo, out, ws);
  } else {
    k_fused<false><<<NBLK, 256, 0, stream>>>(enc, sos, emb, W1, b1, W2, b2,
                                             Wih, bih, Whh, bhh, Wo, bo, out, ws);
  }
}